// Round 11
// baseline (130.476 us; speedup 1.0000x reference)
//
#include <hip/hip_runtime.h>
#include <cstdint>

#define NR 8192
#define DIMK 512
#define NE 8192

// ---------------- MFMA path parameters ----------------
#define GBK 32              // K-step
#define KSTEPS (DIMK / GBK) // 16
#define TILE_BYTES 8192     // 128 rows x 32 k x 2B per K-step image
#define NBLK 64             // 64 col-blocks of 128 codes
#define NCAND 128           // candidate pairs per row (64 nb x 2 wc)
#define DELTA 6.0f          // refine window: bf16 err (~0.5) + key trunc (~2), margin

typedef __bf16 bf16x8 __attribute__((ext_vector_type(8)));
typedef float f32x4 __attribute__((ext_vector_type(4)));

// f32 fallback tiling
#define BM 128
#define BN 128
#define BK 16
#define ESPLIT 16
#define ERANGE (NE / ESPLIT)
#define ETILES (ERANGE / BN)
#define PM 64
#define PN 64
#define PK 16

// ---------------- Kernel: fused prep (enorm + E/X/W bf16 tiled pack) -----
__global__ __launch_bounds__(256) void prep_kernel(
    const float* __restrict__ X, const float* __restrict__ E,
    const float* __restrict__ W,
    uint8_t* __restrict__ Ap, uint8_t* __restrict__ Bp,
    uint8_t* __restrict__ Wp, float* __restrict__ enorm) {
    const int bid = blockIdx.x;
    const int wave = threadIdx.x >> 6;
    const int lane = threadIdx.x & 63;

    const float* src;
    uint8_t* dst;
    int row;
    bool doNorm = false;
    if (bid < NE / 4) {
        row = bid * 4 + wave;
        src = E + (size_t)row * DIMK;
        dst = Bp;
        doNorm = true;
    } else if (bid < NE / 4 + NR / 4) {
        row = (bid - NE / 4) * 4 + wave;
        src = X + (size_t)row * DIMK;
        dst = Ap;
    } else {
        row = (bid - NE / 4 - NR / 4) * 4 + wave;
        src = W + (size_t)row * DIMK;
        dst = Wp;
    }

    float4 f0 = *(const float4*)(src + lane * 8);
    float4 f1 = *(const float4*)(src + lane * 8 + 4);
    float v[8] = {f0.x, f0.y, f0.z, f0.w, f1.x, f1.y, f1.z, f1.w};

    if (doNorm) {
        float s = 0.f;
#pragma unroll
        for (int j = 0; j < 8; ++j) s = fmaf(v[j], v[j], s);
#pragma unroll
        for (int off = 32; off > 0; off >>= 1) s += __shfl_xor(s, off, 64);
        if (lane == 0) enorm[row] = s;
    }

    unsigned short o[8];
#pragma unroll
    for (int j = 0; j < 8; ++j) {
        __bf16 h = (__bf16)v[j];
        o[j] = __builtin_bit_cast(unsigned short, h);
    }
    uint4 u;
    u.x = (uint32_t)o[0] | ((uint32_t)o[1] << 16);
    u.y = (uint32_t)o[2] | ((uint32_t)o[3] << 16);
    u.z = (uint32_t)o[4] | ((uint32_t)o[5] << 16);
    u.w = (uint32_t)o[6] | ((uint32_t)o[7] << 16);
    const int r = row & 127;
    const int kt = lane >> 2;
    const int kk = (lane & 3) * 8;
    size_t base = ((size_t)(row >> 7) * KSTEPS + kt) * TILE_BYTES;
    int byte = (r * 64 + kk * 2) ^ ((r & 7) << 4);
    *(uint4*)(dst + base + byte) = u;
}

// ---------------- Kernel: ||E_e||^2 (f32 fallback path only) -------------
__global__ __launch_bounds__(256) void enorm_kernel(const float* __restrict__ E,
                                                    float* __restrict__ enorm) {
    int wave = threadIdx.x >> 6;
    int lane = threadIdx.x & 63;
    int row = blockIdx.x * 4 + wave;
    const float* er = E + (size_t)row * DIMK;
    float s = 0.f;
#pragma unroll
    for (int k = 0; k < DIMK / 64; ++k) {
        float v = er[lane + k * 64];
        s = fmaf(v, v, s);
    }
#pragma unroll
    for (int off = 32; off > 0; off >>= 1) s += __shfl_down(s, off, 64);
    if (lane == 0) enorm[row] = s;
}

// ---------------- global -> LDS staging (8 KB, 256 threads) ----------------
__device__ __forceinline__ void stage_8k(void* lds, const void* g, int tid) {
    const int wid = tid >> 6;
    const int lane = tid & 63;
    using gu32 = const __attribute__((address_space(1))) uint32_t;
    using lu32 = __attribute__((address_space(3))) uint32_t;
    const uint8_t* gp = (const uint8_t*)g + (size_t)(wid * 1024 + lane * 16);
    uint8_t* lp = (uint8_t*)lds + wid * 1024;
    __builtin_amdgcn_global_load_lds((gu32*)gp, (lu32*)lp, 16, 0, 0);
    __builtin_amdgcn_global_load_lds((gu32*)(gp + 4096), (lu32*)(lp + 4096), 16, 0, 0);
}

// ---------------- 32-bit (value,index) key helpers ----------------
__device__ __forceinline__ unsigned flip32(float v) {
    unsigned b = __float_as_uint(v);
    return b ^ (0x80000000u | (unsigned)((int)b >> 31));
}
__device__ __forceinline__ float unflip32(unsigned b) {
    return __uint_as_float(b ^ (0x80000000u | ~(unsigned)((int)b >> 31)));
}

// ---------------- Kernel: bf16 MFMA dist, 128x256 tile (shared-A) --------
// grid = 2048; each block: one A-tile (128 x-rows) x TWO B-tiles (2x128
// codes) sharing the A stage -> 24 KB staged per K-step for 2x MFMA work
// (arithmetic intensity +33% vs 128x128). Same dbuf loop, same swizzle,
// same swapped-operand lane-local top-2 epilogue (run per B-tile).
__global__ __launch_bounds__(256, 2) void dist_mfma_kernel(
    const uint8_t* __restrict__ Ap, const uint8_t* __restrict__ Bp,
    const float* __restrict__ enorm,
    uint2* __restrict__ candk) {
    __shared__ __align__(16) uint8_t As[2][TILE_BYTES];
    __shared__ __align__(16) uint8_t Bs0[2][TILE_BYTES];
    __shared__ __align__(16) uint8_t Bs1[2][TILE_BYTES];

    const int tid = threadIdx.x;
    const int lane = tid & 63;
    const int wid = tid >> 6;
    const int wr = wid >> 1, wc = wid & 1;
    const int xcd = blockIdx.x & 7;
    const int slot = blockIdx.x >> 3;      // 0..255
    const int mb = slot >> 2;              // 0..63
    const int nb0 = xcd * 8 + (slot & 3);  // first B tile
    const int nb1 = nb0 + 4;               // second B tile (same XCD slice)
    const int lr = lane & 15;
    const int kq = lane >> 4;

    const uint8_t* gA = Ap + (size_t)mb * KSTEPS * TILE_BYTES;
    const uint8_t* gB0 = Bp + (size_t)nb0 * KSTEPS * TILE_BYTES;
    const uint8_t* gB1 = Bp + (size_t)nb1 * KSTEPS * TILE_BYTES;

    int aoff[4], boff[4];
#pragma unroll
    for (int mi = 0; mi < 4; ++mi) {
        int row = wr * 64 + mi * 16 + lr;
        aoff[mi] = (row * 64 + kq * 16) ^ ((row & 7) << 4);
    }
#pragma unroll
    for (int ni = 0; ni < 4; ++ni) {
        int row = wc * 64 + ni * 16 + lr;
        boff[ni] = (row * 64 + kq * 16) ^ ((row & 7) << 4);
    }

    f32x4 acc0[4][4], acc1[4][4];
#pragma unroll
    for (int mi = 0; mi < 4; ++mi)
#pragma unroll
        for (int ni = 0; ni < 4; ++ni) {
            acc0[mi][ni] = (f32x4){0.f, 0.f, 0.f, 0.f};
            acc1[mi][ni] = (f32x4){0.f, 0.f, 0.f, 0.f};
        }

    stage_8k(As[0], gA, tid);
    stage_8k(Bs0[0], gB0, tid);
    stage_8k(Bs1[0], gB1, tid);

    int buf = 0;
    for (int kt = 0; kt < KSTEPS; ++kt) {
        __syncthreads();               // buf fully written (vmcnt drained)
        if (kt + 1 < KSTEPS) {
            stage_8k(As[buf ^ 1], gA + (size_t)(kt + 1) * TILE_BYTES, tid);
            stage_8k(Bs0[buf ^ 1], gB0 + (size_t)(kt + 1) * TILE_BYTES, tid);
            stage_8k(Bs1[buf ^ 1], gB1 + (size_t)(kt + 1) * TILE_BYTES, tid);
        }
        bf16x8 af[4], bf0[4], bf1[4];
#pragma unroll
        for (int mi = 0; mi < 4; ++mi) af[mi] = *(const bf16x8*)(As[buf] + aoff[mi]);
#pragma unroll
        for (int ni = 0; ni < 4; ++ni) bf0[ni] = *(const bf16x8*)(Bs0[buf] + boff[ni]);
#pragma unroll
        for (int ni = 0; ni < 4; ++ni) bf1[ni] = *(const bf16x8*)(Bs1[buf] + boff[ni]);
        // SWAPPED operands: lane holds xrow = lane&15; codes (lane>>4)*4+reg
#pragma unroll
        for (int mi = 0; mi < 4; ++mi)
#pragma unroll
            for (int ni = 0; ni < 4; ++ni)
                acc0[mi][ni] = __builtin_amdgcn_mfma_f32_16x16x32_bf16(
                    bf0[ni], af[mi], acc0[mi][ni], 0, 0, 0);
#pragma unroll
        for (int mi = 0; mi < 4; ++mi)
#pragma unroll
            for (int ni = 0; ni < 4; ++ni)
                acc1[mi][ni] = __builtin_amdgcn_mfma_f32_16x16x32_bf16(
                    bf1[ni], af[mi], acc1[mi][ni], 0, 0, 0);
        buf ^= 1;
    }

    // epilogue per B-tile: s = enorm - 2*acc ; lane-local top-2 + 2 merges
#pragma unroll
    for (int t = 0; t < 2; ++t) {
        const int nb = t ? nb1 : nb0;
        const int e0 = nb * 128 + wc * 64;
        float en[4][4];
#pragma unroll
        for (int ni = 0; ni < 4; ++ni)
#pragma unroll
            for (int reg = 0; reg < 4; ++reg)
                en[ni][reg] = enorm[e0 + ni * 16 + kq * 4 + reg];

#pragma unroll
        for (int mi = 0; mi < 4; ++mi) {
            unsigned k1 = 0xFFFFFFFFu, k2 = 0xFFFFFFFFu;
#pragma unroll
            for (int ni = 0; ni < 4; ++ni)
#pragma unroll
                for (int reg = 0; reg < 4; ++reg) {
                    float a = t ? acc1[mi][ni][reg] : acc0[mi][ni][reg];
                    float s = fmaf(-2.f, a, en[ni][reg]);
                    unsigned key = (flip32(s) & 0xFFFFE000u) |
                                   (unsigned)(e0 + ni * 16 + kq * 4 + reg);
                    unsigned lo = min(k1, key), hi = max(k1, key);
                    k1 = lo;
                    k2 = min(k2, hi);
                }
#pragma unroll
            for (int m = 16; m <= 32; m <<= 1) {
                unsigned o1 = __shfl_xor(k1, m, 64);
                unsigned o2 = __shfl_xor(k2, m, 64);
                unsigned lo = min(k1, o1), hi = max(k1, o1);
                k1 = lo;
                k2 = min(hi, min(k2, o2));
            }
            if (lane < 16) {
                int row = mb * 128 + wr * 64 + mi * 16 + lane;
                candk[(size_t)row * NCAND + nb * 2 + wc] = make_uint2(k1, k2);
            }
        }
    }
}

// ------- Kernel: fp64 refine -> argmin, fused residual pack (bf16) -------
__global__ __launch_bounds__(256) void refine_rpack_kernel(
    const float* __restrict__ X, const float* __restrict__ E,
    const uint2* __restrict__ candk, int* __restrict__ ind,
    uint8_t* __restrict__ Rp) {
    const int wid = threadIdx.x >> 6;
    const int lane = threadIdx.x & 63;
    const int row = blockIdx.x * 4 + wid;

    const uint2* ck = candk + (size_t)row * NCAND;
    uint2 c0 = ck[lane];
    uint2 c1 = ck[lane + 64];
    unsigned keys[4] = {c0.x, c0.y, c1.x, c1.y};

    unsigned kmin = min(min(keys[0], keys[1]), min(keys[2], keys[3]));
#pragma unroll
    for (int off = 32; off > 0; off >>= 1)
        kmin = min(kmin, __shfl_xor(kmin, off, 64));

    const float vmin = unflip32(kmin & 0xFFFFE000u);
    const unsigned kthr = (flip32(vmin + DELTA) & 0xFFFFE000u) | 0x1FFFu;

    unsigned long long msk[4];
    int total = 0;
#pragma unroll
    for (int c = 0; c < 4; ++c) {
        msk[c] = __ballot(keys[c] <= kthr);
        total += __popcll(msk[c]);
    }

    const float* xr = X + (size_t)row * DIMK;
    int besti;
    if (total == 1) {
        besti = (int)(kmin & 0x1FFFu);
    } else {
        double bestd = 1e300;
        int bi = 0x7fffffff;
#pragma unroll 1
        for (int c = 0; c < 4; ++c) {
            unsigned long long mask = msk[c];
            while (mask) {
                int src = __ffsll((long long)mask) - 1;
                mask &= mask - 1;
                unsigned kk = __shfl(keys[c], src, 64);
                int e = (int)(kk & 0x1FFFu);
                const float* er = E + (size_t)e * DIMK;
                double s = 0.0;
#pragma unroll
                for (int j = 0; j < 8; ++j) {
                    double ev = (double)er[lane * 8 + j];
                    double xv = (double)xr[lane * 8 + j];
                    s += ev * (ev - 2.0 * xv);
                }
#pragma unroll
                for (int off = 32; off > 0; off >>= 1)
                    s += __shfl_xor(s, off, 64);
                if (s < bestd || (s == bestd && e < bi)) { bestd = s; bi = e; }
            }
        }
        besti = bi;
    }
    if (lane == 0) ind[row] = besti;

    // fused residual pack: R[row][k] = bf16(x - E[besti]), tiled+swizzled
    const float* er = E + (size_t)besti * DIMK;
    unsigned short o[8];
#pragma unroll
    for (int j = 0; j < 8; ++j) {
        __bf16 h = (__bf16)(xr[lane * 8 + j] - er[lane * 8 + j]);
        o[j] = __builtin_bit_cast(unsigned short, h);
    }
    uint4 u;
    u.x = (uint32_t)o[0] | ((uint32_t)o[1] << 16);
    u.y = (uint32_t)o[2] | ((uint32_t)o[3] << 16);
    u.z = (uint32_t)o[4] | ((uint32_t)o[5] << 16);
    u.w = (uint32_t)o[6] | ((uint32_t)o[7] << 16);
    int mbr = row >> 7, r = row & 127;
    int kt = lane >> 2, kk = (lane & 3) * 8;
    size_t base = ((size_t)mbr * KSTEPS + kt) * TILE_BYTES;
    int byte = (r * 64 + kk * 2) ^ ((r & 7) << 4);
    *(uint4*)(Rp + base + byte) = u;
}

// ------- Kernel: proj via bf16 MFMA: out = X + R @ W^T + b -------
__global__ __launch_bounds__(256, 4) void proj_mfma_kernel(
    const uint8_t* __restrict__ Rp, const uint8_t* __restrict__ Wp,
    const float* __restrict__ X, const float* __restrict__ Bv,
    float* __restrict__ Out) {
    __shared__ __align__(16) uint8_t As[2][TILE_BYTES];
    __shared__ __align__(16) uint8_t Bs[2][TILE_BYTES];

    const int tid = threadIdx.x;
    const int lane = tid & 63;
    const int wid = tid >> 6;
    const int wr = wid >> 1, wc = wid & 1;
    const int mb = blockIdx.x >> 2;   // 0..63 (x rows / 128)
    const int nb = blockIdx.x & 3;    // 0..3  (out cols / 128)
    const int lr = lane & 15;
    const int kq = lane >> 4;

    const uint8_t* gA = Rp + (size_t)mb * KSTEPS * TILE_BYTES;
    const uint8_t* gB = Wp + (size_t)nb * KSTEPS * TILE_BYTES;

    int aoff[4], boff[4];
#pragma unroll
    for (int mi = 0; mi < 4; ++mi) {
        int row = wr * 64 + mi * 16 + lr;
        aoff[mi] = (row * 64 + kq * 16) ^ ((row & 7) << 4);
    }
#pragma unroll
    for (int ni = 0; ni < 4; ++ni) {
        int row = wc * 64 + ni * 16 + lr;
        boff[ni] = (row * 64 + kq * 16) ^ ((row & 7) << 4);
    }

    f32x4 acc[4][4];
#pragma unroll
    for (int mi = 0; mi < 4; ++mi)
#pragma unroll
        for (int ni = 0; ni < 4; ++ni)
            acc[mi][ni] = (f32x4){0.f, 0.f, 0.f, 0.f};

    stage_8k(As[0], gA, tid);
    stage_8k(Bs[0], gB, tid);

    int buf = 0;
    for (int kt = 0; kt < KSTEPS; ++kt) {
        __syncthreads();
        if (kt + 1 < KSTEPS) {
            stage_8k(As[buf ^ 1], gA + (size_t)(kt + 1) * TILE_BYTES, tid);
            stage_8k(Bs[buf ^ 1], gB + (size_t)(kt + 1) * TILE_BYTES, tid);
        }
        bf16x8 af[4], bfr[4];
#pragma unroll
        for (int mi = 0; mi < 4; ++mi) af[mi] = *(const bf16x8*)(As[buf] + aoff[mi]);
#pragma unroll
        for (int ni = 0; ni < 4; ++ni) bfr[ni] = *(const bf16x8*)(Bs[buf] + boff[ni]);
#pragma unroll
        for (int mi = 0; mi < 4; ++mi)
#pragma unroll
            for (int ni = 0; ni < 4; ++ni)
                acc[mi][ni] = __builtin_amdgcn_mfma_f32_16x16x32_bf16(
                    af[mi], bfr[ni], acc[mi][ni], 0, 0, 0);
        buf ^= 1;
    }

    // epilogue: out[row][col] = X[row][col] + acc + bias[col]
    const int col0 = nb * 128 + wc * 64;
    float bias[4];
#pragma unroll
    for (int ni = 0; ni < 4; ++ni) bias[ni] = Bv[col0 + ni * 16 + lr];

#pragma unroll
    for (int mi = 0; mi < 4; ++mi) {
#pragma unroll
        for (int reg = 0; reg < 4; ++reg) {
            int row = mb * 128 + wr * 64 + mi * 16 + kq * 4 + reg;
            const float* xrow = X + (size_t)row * DIMK;
            float* orow = Out + (size_t)row * DIMK;
#pragma unroll
            for (int ni = 0; ni < 4; ++ni) {
                int col = col0 + ni * 16 + lr;
                orow[col] = xrow[col] + acc[mi][ni][reg] + bias[ni];
            }
        }
    }
}

// ------- f32 fallback: fused dist matmul + per-split argmin -------
__global__ __launch_bounds__(256) void dist_argmin_kernel(
    const float* __restrict__ X, const float* __restrict__ E,
    const float* __restrict__ enorm,
    float* __restrict__ pval, int* __restrict__ pidx) {
    __shared__ float xs[BK][BM + 4];
    __shared__ float es[BK][BN + 4];
    __shared__ float rv[BM][17];
    __shared__ int ri[BM][17];

    const int tid = threadIdx.x;
    const int row0 = blockIdx.y * BM;
    const int e_base = blockIdx.x * ERANGE;
    const int tx = tid & 15;
    const int ty = tid >> 4;

    float minv[8];
    int mini[8];
#pragma unroll
    for (int i = 0; i < 8; ++i) { minv[i] = 3.4e38f; mini[i] = 0; }

    const int lm = tid >> 1;
    const int lk = (tid & 1) * 8;

    for (int et = 0; et < ETILES; ++et) {
        const int e0 = e_base + et * BN;
        float acc[8][8];
#pragma unroll
        for (int i = 0; i < 8; ++i)
#pragma unroll
            for (int j = 0; j < 8; ++j) acc[i][j] = 0.f;

        for (int kt = 0; kt < DIMK / BK; ++kt) {
            const int k0 = kt * BK;
            {
                const float* src = X + (size_t)(row0 + lm) * DIMK + k0 + lk;
                float4 v0 = *(const float4*)(src);
                float4 v1 = *(const float4*)(src + 4);
                xs[lk + 0][lm] = v0.x; xs[lk + 1][lm] = v0.y;
                xs[lk + 2][lm] = v0.z; xs[lk + 3][lm] = v0.w;
                xs[lk + 4][lm] = v1.x; xs[lk + 5][lm] = v1.y;
                xs[lk + 6][lm] = v1.z; xs[lk + 7][lm] = v1.w;
            }
            {
                const float* src = E + (size_t)(e0 + lm) * DIMK + k0 + lk;
                float4 v0 = *(const float4*)(src);
                float4 v1 = *(const float4*)(src + 4);
                es[lk + 0][lm] = v0.x; es[lk + 1][lm] = v0.y;
                es[lk + 2][lm] = v0.z; es[lk + 3][lm] = v0.w;
                es[lk + 4][lm] = v1.x; es[lk + 5][lm] = v1.y;
                es[lk + 6][lm] = v1.z; es[lk + 7][lm] = v1.w;
            }
            __syncthreads();
#pragma unroll
            for (int k = 0; k < BK; ++k) {
                float4 a0 = *(const float4*)&xs[k][ty * 8];
                float4 a1 = *(const float4*)&xs[k][ty * 8 + 4];
                float4 b0 = *(const float4*)&es[k][tx * 8];
                float4 b1 = *(const float4*)&es[k][tx * 8 + 4];
                float av[8] = {a0.x, a0.y, a0.z, a0.w, a1.x, a1.y, a1.z, a1.w};
                float bv[8] = {b0.x, b0.y, b0.z, b0.w, b1.x, b1.y, b1.z, b1.w};
#pragma unroll
                for (int i = 0; i < 8; ++i)
#pragma unroll
                    for (int j = 0; j < 8; ++j)
                        acc[i][j] = fmaf(av[i], bv[j], acc[i][j]);
            }
            __syncthreads();
        }
#pragma unroll
        for (int j = 0; j < 8; ++j) {
            const int e = e0 + tx * 8 + j;
            const float en = enorm[e];
#pragma unroll
            for (int i = 0; i < 8; ++i) {
                const float s = fmaf(-2.f, acc[i][j], en);
                if (s < minv[i]) { minv[i] = s; mini[i] = e; }
            }
        }
    }
#pragma unroll
    for (int i = 0; i < 8; ++i) {
        rv[ty * 8 + i][tx] = minv[i];
        ri[ty * 8 + i][tx] = mini[i];
    }
    __syncthreads();
    if (tid < BM) {
        float bv = rv[tid][0];
        int bi = ri[tid][0];
#pragma unroll
        for (int t = 1; t < 16; ++t) {
            float vv = rv[tid][t];
            int ix = ri[tid][t];
            if (vv < bv || (vv == bv && ix < bi)) { bv = vv; bi = ix; }
        }
        const int row = row0 + tid;
        pval[(size_t)row * ESPLIT + blockIdx.x] = bv;
        pidx[(size_t)row * ESPLIT + blockIdx.x] = bi;
    }
}

__global__ __launch_bounds__(256) void reduce_argmin_kernel(
    const float* __restrict__ pval, const int* __restrict__ pidx,
    int* __restrict__ ind) {
    int r = blockIdx.x * blockDim.x + threadIdx.x;
    if (r >= NR) return;
    float bv = pval[(size_t)r * ESPLIT];
    int bi = pidx[(size_t)r * ESPLIT];
#pragma unroll
    for (int s = 1; s < ESPLIT; ++s) {
        float v = pval[(size_t)r * ESPLIT + s];
        int ix = pidx[(size_t)r * ESPLIT + s];
        if (v < bv || (v == bv && ix < bi)) { bv = v; bi = ix; }
    }
    ind[r] = bi;
}

// ------- f32 fallback proj: out = x + (x - E[ind]) @ W^T + b -------
__global__ __launch_bounds__(256) void proj_kernel(
    const float* __restrict__ X, const float* __restrict__ E,
    const int* __restrict__ ind,
    const float* __restrict__ W, const float* __restrict__ Bv,
    float* __restrict__ Out) {
    __shared__ float as_[PK][PM + 4];
    __shared__ float bs[PK][PN + 4];
    __shared__ int inds[PM];

    const int tid = threadIdx.x;
    const int row0 = blockIdx.y * PM;
    const int col0 = blockIdx.x * PN;

    if (tid < PM) inds[tid] = ind[row0 + tid];
    __syncthreads();

    const int tx = tid & 15;
    const int ty = tid >> 4;

    float acc[4][4];
#pragma unroll
    for (int i = 0; i < 4; ++i)
#pragma unroll
        for (int j = 0; j < 4; ++j) acc[i][j] = 0.f;

    const int lm = tid >> 2;
    const int lk = (tid & 3) * 4;

    for (int kt = 0; kt < DIMK / PK; ++kt) {
        const int k0 = kt * PK;
        {
            float4 xv = *(const float4*)(X + (size_t)(row0 + lm) * DIMK + k0 + lk);
            float4 qv = *(const float4*)(E + (size_t)inds[lm] * DIMK + k0 + lk);
            as_[lk + 0][lm] = xv.x - qv.x;
            as_[lk + 1][lm] = xv.y - qv.y;
            as_[lk + 2][lm] = xv.z - qv.z;
            as_[lk + 3][lm] = xv.w - qv.w;
        }
        {
            float4 wv = *(const float4*)(W + (size_t)(col0 + lm) * DIMK + k0 + lk);
            bs[lk + 0][lm] = wv.x; bs[lk + 1][lm] = wv.y;
            bs[lk + 2][lm] = wv.z; bs[lk + 3][lm] = wv.w;
        }
        __syncthreads();
#pragma unroll
        for (int k = 0; k < PK; ++k) {
            float4 a = *(const float4*)&as_[k][ty * 4];
            float4 b = *(const float4*)&bs[k][tx * 4];
            float av[4] = {a.x, a.y, a.z, a.w};
            float bvv[4] = {b.x, b.y, b.z, b.w};
#pragma unroll
            for (int i = 0; i < 4; ++i)
#pragma unroll
                for (int j = 0; j < 4; ++j)
                    acc[i][j] = fmaf(av[i], bvv[j], acc[i][j]);
        }
        __syncthreads();
    }

#pragma unroll
    for (int j = 0; j < 4; ++j) {
        const int col = col0 + tx * 4 + j;
        const float bias = Bv[col];
#pragma unroll
        for (int i = 0; i < 4; ++i) {
            const int row = row0 + ty * 4 + i;
            Out[(size_t)row * DIMK + col] =
                X[(size_t)row * DIMK + col] + acc[i][j] + bias;
        }
    }
}

extern "C" void kernel_launch(void* const* d_in, const int* in_sizes, int n_in,
                              void* d_out, int out_size, void* d_ws, size_t ws_size,
                              hipStream_t stream) {
    const float* X = (const float*)d_in[0];
    const float* E = (const float*)d_in[1];
    const float* W = (const float*)d_in[2];
    const float* B = (const float*)d_in[3];
    float* out = (float*)d_out;

    const size_t packBytes = (size_t)NR * DIMK * 2;        // 8 MB each
    const size_t wPackBytes = (size_t)DIMK * DIMK * 2;     // 0.5 MB
    const size_t candBytes = (size_t)NR * NCAND * 8;       // 8 MB
    const size_t needMFMA =
        packBytes * 3 + wPackBytes + NE * 4 + candBytes + NR * 4 + 64;

    if (ws_size >= needMFMA) {
        uint8_t* Ap = (uint8_t*)d_ws;
        uint8_t* Bp = Ap + packBytes;
        uint8_t* Rp = Bp + packBytes;
        uint8_t* Wp = Rp + packBytes;
        float* enorm = (float*)(Wp + wPackBytes);
        uint2* candk = (uint2*)(enorm + NE);
        int* ind = (int*)((uint8_t*)candk + candBytes);

        hipLaunchKernelGGL(prep_kernel, dim3(NE / 4 + NR / 4 + DIMK / 4), dim3(256),
                           0, stream, X, E, W, Ap, Bp, Wp, enorm);
        hipLaunchKernelGGL(dist_mfma_kernel, dim3(2048), dim3(256), 0,
                           stream, Ap, Bp, enorm, candk);
        hipLaunchKernelGGL(refine_rpack_kernel, dim3(NR / 4), dim3(256), 0, stream,
                           X, E, candk, ind, Rp);
        hipLaunchKernelGGL(proj_mfma_kernel, dim3(256), dim3(256), 0, stream,
                           Rp, Wp, X, B, out);
    } else {
        float* enorm = (float*)d_ws;
        float* pval = enorm + NE;
        int* pidx = (int*)(pval + (size_t)NR * ESPLIT);
        int* ind = pidx + (size_t)NR * ESPLIT;

        hipLaunchKernelGGL(enorm_kernel, dim3(NE / 4), dim3(256), 0, stream, E, enorm);
        hipLaunchKernelGGL(dist_argmin_kernel, dim3(ESPLIT, NR / BM), dim3(256), 0,
                           stream, X, E, enorm, pval, pidx);
        hipLaunchKernelGGL(reduce_argmin_kernel, dim3(NR / 256), dim3(256), 0, stream,
                           pval, pidx, ind);
        hipLaunchKernelGGL(proj_kernel, dim3(DIMK / PN, NR / PM), dim3(256), 0, stream,
                           X, E, ind, W, B, out);
    }
}

// Round 12
// 115.580 us; speedup vs baseline: 1.1289x; 1.1289x over previous
//
#include <hip/hip_runtime.h>
#include <cstdint>

#define NR 8192
#define DIMK 512
#define NE 8192

// ---------------- MFMA path parameters ----------------
#define KSTEPS 16             // K=512 / 32
#define TILE_BYTES 8192       // 128-row k-step image (Wp, Rp -> proj)
#define TB256 16384           // 256-row k-step image (Ap, Bp -> dist)
#define NCAND 128             // candidate pairs per row
#define DELTA 6.0f            // refine window

typedef __bf16 bf16x8 __attribute__((ext_vector_type(8)));
typedef float f32x4 __attribute__((ext_vector_type(4)));

// f32 fallback tiling
#define BM 128
#define BN 128
#define BK 16
#define ESPLIT 16
#define ERANGE (NE / ESPLIT)
#define ETILES (ERANGE / BN)
#define PM 64
#define PN 64
#define PK 16

// ---------------- Kernel: fused prep (enorm + E/X/W bf16 tiled pack) -----
// E,X -> 256-row images (dist); W -> 128-row images (proj).
__global__ __launch_bounds__(256) void prep_kernel(
    const float* __restrict__ X, const float* __restrict__ E,
    const float* __restrict__ W,
    uint8_t* __restrict__ Ap, uint8_t* __restrict__ Bp,
    uint8_t* __restrict__ Wp, float* __restrict__ enorm) {
    const int bid = blockIdx.x;
    const int wave = threadIdx.x >> 6;
    const int lane = threadIdx.x & 63;

    const float* src;
    uint8_t* dst;
    int row;
    bool doNorm = false, wide = true;
    if (bid < NE / 4) {
        row = bid * 4 + wave;
        src = E + (size_t)row * DIMK;
        dst = Bp;
        doNorm = true;
    } else if (bid < NE / 4 + NR / 4) {
        row = (bid - NE / 4) * 4 + wave;
        src = X + (size_t)row * DIMK;
        dst = Ap;
    } else {
        row = (bid - NE / 4 - NR / 4) * 4 + wave;
        src = W + (size_t)row * DIMK;
        dst = Wp;
        wide = false;
    }

    float4 f0 = *(const float4*)(src + lane * 8);
    float4 f1 = *(const float4*)(src + lane * 8 + 4);
    float v[8] = {f0.x, f0.y, f0.z, f0.w, f1.x, f1.y, f1.z, f1.w};

    if (doNorm) {
        float s = 0.f;
#pragma unroll
        for (int j = 0; j < 8; ++j) s = fmaf(v[j], v[j], s);
#pragma unroll
        for (int off = 32; off > 0; off >>= 1) s += __shfl_xor(s, off, 64);
        if (lane == 0) enorm[row] = s;
    }

    unsigned short o[8];
#pragma unroll
    for (int j = 0; j < 8; ++j) {
        __bf16 h = (__bf16)v[j];
        o[j] = __builtin_bit_cast(unsigned short, h);
    }
    uint4 u;
    u.x = (uint32_t)o[0] | ((uint32_t)o[1] << 16);
    u.y = (uint32_t)o[2] | ((uint32_t)o[3] << 16);
    u.z = (uint32_t)o[4] | ((uint32_t)o[5] << 16);
    u.w = (uint32_t)o[6] | ((uint32_t)o[7] << 16);
    const int kt = lane >> 2;
    const int kk = (lane & 3) * 8;
    if (wide) {
        const int r = row & 255;
        size_t base = ((size_t)(row >> 8) * KSTEPS + kt) * TB256;
        int byte = (r * 64 + kk * 2) ^ ((r & 7) << 4);
        *(uint4*)(dst + base + byte) = u;
    } else {
        const int r = row & 127;
        size_t base = ((size_t)(row >> 7) * KSTEPS + kt) * TILE_BYTES;
        int byte = (r * 64 + kk * 2) ^ ((r & 7) << 4);
        *(uint4*)(dst + base + byte) = u;
    }
}

// ---------------- Kernel: ||E_e||^2 (f32 fallback path only) -------------
__global__ __launch_bounds__(256) void enorm_kernel(const float* __restrict__ E,
                                                    float* __restrict__ enorm) {
    int wave = threadIdx.x >> 6;
    int lane = threadIdx.x & 63;
    int row = blockIdx.x * 4 + wave;
    const float* er = E + (size_t)row * DIMK;
    float s = 0.f;
#pragma unroll
    for (int k = 0; k < DIMK / 64; ++k) {
        float v = er[lane + k * 64];
        s = fmaf(v, v, s);
    }
#pragma unroll
    for (int off = 32; off > 0; off >>= 1) s += __shfl_down(s, off, 64);
    if (lane == 0) enorm[row] = s;
}

// ------- global -> LDS staging: 8 KB by 256 thr (proj) / 16 KB by 512 thr -
__device__ __forceinline__ void stage_8k(void* lds, const void* g, int tid) {
    using gu32 = const __attribute__((address_space(1))) uint32_t;
    using lu32 = __attribute__((address_space(3))) uint32_t;
    const uint8_t* gp = (const uint8_t*)g + (size_t)tid * 16;
    uint8_t* lp = (uint8_t*)lds + tid * 16;
    __builtin_amdgcn_global_load_lds((gu32*)gp, (lu32*)lp, 16, 0, 0);
    __builtin_amdgcn_global_load_lds((gu32*)(gp + 4096), (lu32*)(lp + 4096), 16, 0, 0);
}
__device__ __forceinline__ void stage_16k(void* lds, const void* g, int tid) {
    using gu32 = const __attribute__((address_space(1))) uint32_t;
    using lu32 = __attribute__((address_space(3))) uint32_t;
    const uint8_t* gp = (const uint8_t*)g + (size_t)tid * 16;
    uint8_t* lp = (uint8_t*)lds + tid * 16;
    __builtin_amdgcn_global_load_lds((gu32*)gp, (lu32*)lp, 16, 0, 0);
    __builtin_amdgcn_global_load_lds((gu32*)(gp + 8192), (lu32*)(lp + 8192), 16, 0, 0);
}

// ---------------- 32-bit (value,index) key helpers ----------------
__device__ __forceinline__ unsigned flip32(float v) {
    unsigned b = __float_as_uint(v);
    return b ^ (0x80000000u | (unsigned)((int)b >> 31));
}
__device__ __forceinline__ float unflip32(unsigned b) {
    return __uint_as_float(b ^ (0x80000000u | ~(unsigned)((int)b >> 31)));
}

// ------- Kernel: bf16 MFMA dist, 256x256 tile, 8 waves, 4-slot LDS ring ---
// grid = 1024 x 512 thr. Depth-3 prefetch, counted vmcnt(8) + ONE barrier
// per K-step (never drains to 0 until tail). Race-safety: slot distance 3
// of 4; stage issued post-barrier; ds_reads consumed pre-barrier (r5/r6
// HW-verified discipline). Swapped operands -> lane-local top-2, u32 keys.
__global__ __launch_bounds__(512, 2) void dist_mfma_kernel(
    const uint8_t* __restrict__ Ap, const uint8_t* __restrict__ Bp,
    const float* __restrict__ enorm,
    uint2* __restrict__ candk) {
    __shared__ __align__(16) uint8_t As[4][TB256];
    __shared__ __align__(16) uint8_t Bs[4][TB256];

    const int tid = threadIdx.x;
    const int lane = tid & 63;
    const int wid = tid >> 6;          // 0..7
    const int wr = wid >> 2;           // 0..1 (128-row half)
    const int wn = wid & 3;            // 0..3 (64-col quarter)
    const int xcd = blockIdx.x & 7;
    const int slotid = blockIdx.x >> 3;      // 0..127
    const int mb = slotid >> 2;              // 0..31 (256 x-rows)
    const int nbb = xcd * 4 + (slotid & 3);  // 0..31 (256 codes; 1MB/XCD slice)
    const int lr = lane & 15;
    const int kq = lane >> 4;

    const uint8_t* gA = Ap + (size_t)mb * KSTEPS * TB256;
    const uint8_t* gB = Bp + (size_t)nbb * KSTEPS * TB256;

    int aoff[8], boff[4];
#pragma unroll
    for (int mi = 0; mi < 8; ++mi) {
        int row = wr * 128 + mi * 16 + lr;
        aoff[mi] = (row * 64 + kq * 16) ^ ((row & 7) << 4);
    }
#pragma unroll
    for (int ni = 0; ni < 4; ++ni) {
        int row = wn * 64 + ni * 16 + lr;
        boff[ni] = (row * 64 + kq * 16) ^ ((row & 7) << 4);
    }

    f32x4 acc[8][4];
#pragma unroll
    for (int mi = 0; mi < 8; ++mi)
#pragma unroll
        for (int ni = 0; ni < 4; ++ni)
            acc[mi][ni] = (f32x4){0.f, 0.f, 0.f, 0.f};

    // prologue: stage K-tiles 0,1,2 (12 outstanding loads/wave)
#pragma unroll
    for (int p = 0; p < 3; ++p) {
        stage_16k(As[p], gA + (size_t)p * TB256, tid);
        stage_16k(Bs[p], gB + (size_t)p * TB256, tid);
    }

#pragma unroll
    for (int kt = 0; kt < KSTEPS; ++kt) {
        // wait own K-tile kt loads (oldest 4), then sync all waves
        if (kt <= KSTEPS - 3)
            asm volatile("s_waitcnt vmcnt(8)\n\ts_barrier" ::: "memory");
        else if (kt == KSTEPS - 2)
            asm volatile("s_waitcnt vmcnt(4)\n\ts_barrier" ::: "memory");
        else
            asm volatile("s_waitcnt vmcnt(0)\n\ts_barrier" ::: "memory");

        if (kt + 3 < KSTEPS) {   // prefetch into slot freed last iteration
            stage_16k(As[(kt + 3) & 3], gA + (size_t)(kt + 3) * TB256, tid);
            stage_16k(Bs[(kt + 3) & 3], gB + (size_t)(kt + 3) * TB256, tid);
        }

        const uint8_t* as_ = As[kt & 3];
        const uint8_t* bs_ = Bs[kt & 3];
        bf16x8 af[8], bf[4];
#pragma unroll
        for (int mi = 0; mi < 8; ++mi) af[mi] = *(const bf16x8*)(as_ + aoff[mi]);
#pragma unroll
        for (int ni = 0; ni < 4; ++ni) bf[ni] = *(const bf16x8*)(bs_ + boff[ni]);

        __builtin_amdgcn_s_setprio(1);
        // SWAPPED operands: lane holds xrow = lane&15; codes (lane>>4)*4+reg
#pragma unroll
        for (int mi = 0; mi < 8; ++mi)
#pragma unroll
            for (int ni = 0; ni < 4; ++ni)
                acc[mi][ni] = __builtin_amdgcn_mfma_f32_16x16x32_bf16(
                    bf[ni], af[mi], acc[mi][ni], 0, 0, 0);
        __builtin_amdgcn_s_setprio(0);
    }

    // epilogue: s = enorm - 2*acc ; lane-local top-2 over wave's 64 cols,
    // 2 shuffle-merge rounds, direct global write (no LDS, no barrier).
    const int e0 = nbb * 256 + wn * 64;
    float en[4][4];
#pragma unroll
    for (int ni = 0; ni < 4; ++ni)
#pragma unroll
        for (int reg = 0; reg < 4; ++reg)
            en[ni][reg] = enorm[e0 + ni * 16 + kq * 4 + reg];

    const int nb = nbb * 2 + (wn >> 1);
#pragma unroll
    for (int mi = 0; mi < 8; ++mi) {
        unsigned k1 = 0xFFFFFFFFu, k2 = 0xFFFFFFFFu;
#pragma unroll
        for (int ni = 0; ni < 4; ++ni)
#pragma unroll
            for (int reg = 0; reg < 4; ++reg) {
                float s = fmaf(-2.f, acc[mi][ni][reg], en[ni][reg]);
                unsigned key = (flip32(s) & 0xFFFFE000u) |
                               (unsigned)(e0 + ni * 16 + kq * 4 + reg);
                unsigned lo = min(k1, key), hi = max(k1, key);
                k1 = lo;
                k2 = min(k2, hi);
            }
#pragma unroll
        for (int m = 16; m <= 32; m <<= 1) {
            unsigned o1 = __shfl_xor(k1, m, 64);
            unsigned o2 = __shfl_xor(k2, m, 64);
            unsigned lo = min(k1, o1), hi = max(k1, o1);
            k1 = lo;
            k2 = min(hi, min(k2, o2));
        }
        if (lane < 16) {
            int row = mb * 256 + wr * 128 + mi * 16 + lane;
            candk[(size_t)row * NCAND + nb * 2 + (wn & 1)] = make_uint2(k1, k2);
        }
    }
}

// ------- Kernel: fp64 refine -> argmin, fused residual pack (bf16) -------
__global__ __launch_bounds__(256) void refine_rpack_kernel(
    const float* __restrict__ X, const float* __restrict__ E,
    const uint2* __restrict__ candk, int* __restrict__ ind,
    uint8_t* __restrict__ Rp) {
    const int wid = threadIdx.x >> 6;
    const int lane = threadIdx.x & 63;
    const int row = blockIdx.x * 4 + wid;

    const uint2* ck = candk + (size_t)row * NCAND;
    uint2 c0 = ck[lane];
    uint2 c1 = ck[lane + 64];
    unsigned keys[4] = {c0.x, c0.y, c1.x, c1.y};

    unsigned kmin = min(min(keys[0], keys[1]), min(keys[2], keys[3]));
#pragma unroll
    for (int off = 32; off > 0; off >>= 1)
        kmin = min(kmin, __shfl_xor(kmin, off, 64));

    const float vmin = unflip32(kmin & 0xFFFFE000u);
    const unsigned kthr = (flip32(vmin + DELTA) & 0xFFFFE000u) | 0x1FFFu;

    unsigned long long msk[4];
    int total = 0;
#pragma unroll
    for (int c = 0; c < 4; ++c) {
        msk[c] = __ballot(keys[c] <= kthr);
        total += __popcll(msk[c]);
    }

    const float* xr = X + (size_t)row * DIMK;
    int besti;
    if (total == 1) {
        besti = (int)(kmin & 0x1FFFu);
    } else {
        double bestd = 1e300;
        int bi = 0x7fffffff;
#pragma unroll 1
        for (int c = 0; c < 4; ++c) {
            unsigned long long mask = msk[c];
            while (mask) {
                int src = __ffsll((long long)mask) - 1;
                mask &= mask - 1;
                unsigned kk = __shfl(keys[c], src, 64);
                int e = (int)(kk & 0x1FFFu);
                const float* er = E + (size_t)e * DIMK;
                double s = 0.0;
#pragma unroll
                for (int j = 0; j < 8; ++j) {
                    double ev = (double)er[lane * 8 + j];
                    double xv = (double)xr[lane * 8 + j];
                    s += ev * (ev - 2.0 * xv);
                }
#pragma unroll
                for (int off = 32; off > 0; off >>= 1)
                    s += __shfl_xor(s, off, 64);
                if (s < bestd || (s == bestd && e < bi)) { bestd = s; bi = e; }
            }
        }
        besti = bi;
    }
    if (lane == 0) ind[row] = besti;

    // fused residual pack: R[row][k] = bf16(x - E[besti]), 128-row images
    const float* er = E + (size_t)besti * DIMK;
    unsigned short o[8];
#pragma unroll
    for (int j = 0; j < 8; ++j) {
        __bf16 h = (__bf16)(xr[lane * 8 + j] - er[lane * 8 + j]);
        o[j] = __builtin_bit_cast(unsigned short, h);
    }
    uint4 u;
    u.x = (uint32_t)o[0] | ((uint32_t)o[1] << 16);
    u.y = (uint32_t)o[2] | ((uint32_t)o[3] << 16);
    u.z = (uint32_t)o[4] | ((uint32_t)o[5] << 16);
    u.w = (uint32_t)o[6] | ((uint32_t)o[7] << 16);
    int mbr = row >> 7, r = row & 127;
    int kt = lane >> 2, kk = (lane & 3) * 8;
    size_t base = ((size_t)mbr * KSTEPS + kt) * TILE_BYTES;
    int byte = (r * 64 + kk * 2) ^ ((r & 7) << 4);
    *(uint4*)(Rp + base + byte) = u;
}

// ------- Kernel: proj via bf16 MFMA: out = X + R @ W^T + b -------
__global__ __launch_bounds__(256, 4) void proj_mfma_kernel(
    const uint8_t* __restrict__ Rp, const uint8_t* __restrict__ Wp,
    const float* __restrict__ X, const float* __restrict__ Bv,
    float* __restrict__ Out) {
    __shared__ __align__(16) uint8_t As[2][TILE_BYTES];
    __shared__ __align__(16) uint8_t Bs[2][TILE_BYTES];

    const int tid = threadIdx.x;
    const int lane = tid & 63;
    const int wid = tid >> 6;
    const int wr = wid >> 1, wc = wid & 1;
    const int mb = blockIdx.x >> 2;   // 0..63 (x rows / 128)
    const int nb = blockIdx.x & 3;    // 0..3  (out cols / 128)
    const int lr = lane & 15;
    const int kq = lane >> 4;

    const uint8_t* gA = Rp + (size_t)mb * KSTEPS * TILE_BYTES;
    const uint8_t* gB = Wp + (size_t)nb * KSTEPS * TILE_BYTES;

    int aoff[4], boff[4];
#pragma unroll
    for (int mi = 0; mi < 4; ++mi) {
        int row = wr * 64 + mi * 16 + lr;
        aoff[mi] = (row * 64 + kq * 16) ^ ((row & 7) << 4);
    }
#pragma unroll
    for (int ni = 0; ni < 4; ++ni) {
        int row = wc * 64 + ni * 16 + lr;
        boff[ni] = (row * 64 + kq * 16) ^ ((row & 7) << 4);
    }

    f32x4 acc[4][4];
#pragma unroll
    for (int mi = 0; mi < 4; ++mi)
#pragma unroll
        for (int ni = 0; ni < 4; ++ni)
            acc[mi][ni] = (f32x4){0.f, 0.f, 0.f, 0.f};

    stage_8k(As[0], gA, tid);
    stage_8k(Bs[0], gB, tid);

    int buf = 0;
    for (int kt = 0; kt < KSTEPS; ++kt) {
        __syncthreads();
        if (kt + 1 < KSTEPS) {
            stage_8k(As[buf ^ 1], gA + (size_t)(kt + 1) * TILE_BYTES, tid);
            stage_8k(Bs[buf ^ 1], gB + (size_t)(kt + 1) * TILE_BYTES, tid);
        }
        bf16x8 af[4], bfr[4];
#pragma unroll
        for (int mi = 0; mi < 4; ++mi) af[mi] = *(const bf16x8*)(As[buf] + aoff[mi]);
#pragma unroll
        for (int ni = 0; ni < 4; ++ni) bfr[ni] = *(const bf16x8*)(Bs[buf] + boff[ni]);
#pragma unroll
        for (int mi = 0; mi < 4; ++mi)
#pragma unroll
            for (int ni = 0; ni < 4; ++ni)
                acc[mi][ni] = __builtin_amdgcn_mfma_f32_16x16x32_bf16(
                    af[mi], bfr[ni], acc[mi][ni], 0, 0, 0);
        buf ^= 1;
    }

    // epilogue: out[row][col] = X[row][col] + acc + bias[col]
    const int col0 = nb * 128 + wc * 64;
    float bias[4];
#pragma unroll
    for (int ni = 0; ni < 4; ++ni) bias[ni] = Bv[col0 + ni * 16 + lr];

#pragma unroll
    for (int mi = 0; mi < 4; ++mi) {
#pragma unroll
        for (int reg = 0; reg < 4; ++reg) {
            int row = mb * 128 + wr * 64 + mi * 16 + kq * 4 + reg;
            const float* xrow = X + (size_t)row * DIMK;
            float* orow = Out + (size_t)row * DIMK;
#pragma unroll
            for (int ni = 0; ni < 4; ++ni) {
                int col = col0 + ni * 16 + lr;
                orow[col] = xrow[col] + acc[mi][ni][reg] + bias[ni];
            }
        }
    }
}

// ------- f32 fallback: fused dist matmul + per-split argmin -------
__global__ __launch_bounds__(256) void dist_argmin_kernel(
    const float* __restrict__ X, const float* __restrict__ E,
    const float* __restrict__ enorm,
    float* __restrict__ pval, int* __restrict__ pidx) {
    __shared__ float xs[BK][BM + 4];
    __shared__ float es[BK][BN + 4];
    __shared__ float rv[BM][17];
    __shared__ int ri[BM][17];

    const int tid = threadIdx.x;
    const int row0 = blockIdx.y * BM;
    const int e_base = blockIdx.x * ERANGE;
    const int tx = tid & 15;
    const int ty = tid >> 4;

    float minv[8];
    int mini[8];
#pragma unroll
    for (int i = 0; i < 8; ++i) { minv[i] = 3.4e38f; mini[i] = 0; }

    const int lm = tid >> 1;
    const int lk = (tid & 1) * 8;

    for (int et = 0; et < ETILES; ++et) {
        const int e0 = e_base + et * BN;
        float acc[8][8];
#pragma unroll
        for (int i = 0; i < 8; ++i)
#pragma unroll
            for (int j = 0; j < 8; ++j) acc[i][j] = 0.f;

        for (int kt = 0; kt < DIMK / BK; ++kt) {
            const int k0 = kt * BK;
            {
                const float* src = X + (size_t)(row0 + lm) * DIMK + k0 + lk;
                float4 v0 = *(const float4*)(src);
                float4 v1 = *(const float4*)(src + 4);
                xs[lk + 0][lm] = v0.x; xs[lk + 1][lm] = v0.y;
                xs[lk + 2][lm] = v0.z; xs[lk + 3][lm] = v0.w;
                xs[lk + 4][lm] = v1.x; xs[lk + 5][lm] = v1.y;
                xs[lk + 6][lm] = v1.z; xs[lk + 7][lm] = v1.w;
            }
            {
                const float* src = E + (size_t)(e0 + lm) * DIMK + k0 + lk;
                float4 v0 = *(const float4*)(src);
                float4 v1 = *(const float4*)(src + 4);
                es[lk + 0][lm] = v0.x; es[lk + 1][lm] = v0.y;
                es[lk + 2][lm] = v0.z; es[lk + 3][lm] = v0.w;
                es[lk + 4][lm] = v1.x; es[lk + 5][lm] = v1.y;
                es[lk + 6][lm] = v1.z; es[lk + 7][lm] = v1.w;
            }
            __syncthreads();
#pragma unroll
            for (int k = 0; k < BK; ++k) {
                float4 a0 = *(const float4*)&xs[k][ty * 8];
                float4 a1 = *(const float4*)&xs[k][ty * 8 + 4];
                float4 b0 = *(const float4*)&es[k][tx * 8];
                float4 b1 = *(const float4*)&es[k][tx * 8 + 4];
                float av[8] = {a0.x, a0.y, a0.z, a0.w, a1.x, a1.y, a1.z, a1.w};
                float bv[8] = {b0.x, b0.y, b0.z, b0.w, b1.x, b1.y, b1.z, b1.w};
#pragma unroll
                for (int i = 0; i < 8; ++i)
#pragma unroll
                    for (int j = 0; j < 8; ++j)
                        acc[i][j] = fmaf(av[i], bv[j], acc[i][j]);
            }
            __syncthreads();
        }
#pragma unroll
        for (int j = 0; j < 8; ++j) {
            const int e = e0 + tx * 8 + j;
            const float en = enorm[e];
#pragma unroll
            for (int i = 0; i < 8; ++i) {
                const float s = fmaf(-2.f, acc[i][j], en);
                if (s < minv[i]) { minv[i] = s; mini[i] = e; }
            }
        }
    }
#pragma unroll
    for (int i = 0; i < 8; ++i) {
        rv[ty * 8 + i][tx] = minv[i];
        ri[ty * 8 + i][tx] = mini[i];
    }
    __syncthreads();
    if (tid < BM) {
        float bv = rv[tid][0];
        int bi = ri[tid][0];
#pragma unroll
        for (int t = 1; t < 16; ++t) {
            float vv = rv[tid][t];
            int ix = ri[tid][t];
            if (vv < bv || (vv == bv && ix < bi)) { bv = vv; bi = ix; }
        }
        const int row = row0 + tid;
        pval[(size_t)row * ESPLIT + blockIdx.x] = bv;
        pidx[(size_t)row * ESPLIT + blockIdx.x] = bi;
    }
}

__global__ __launch_bounds__(256) void reduce_argmin_kernel(
    const float* __restrict__ pval, const int* __restrict__ pidx,
    int* __restrict__ ind) {
    int r = blockIdx.x * blockDim.x + threadIdx.x;
    if (r >= NR) return;
    float bv = pval[(size_t)r * ESPLIT];
    int bi = pidx[(size_t)r * ESPLIT];
#pragma unroll
    for (int s = 1; s < ESPLIT; ++s) {
        float v = pval[(size_t)r * ESPLIT + s];
        int ix = pidx[(size_t)r * ESPLIT + s];
        if (v < bv || (v == bv && ix < bi)) { bv = v; bi = ix; }
    }
    ind[r] = bi;
}

// ------- f32 fallback proj: out = x + (x - E[ind]) @ W^T + b -------
__global__ __launch_bounds__(256) void proj_kernel(
    const float* __restrict__ X, const float* __restrict__ E,
    const int* __restrict__ ind,
    const float* __restrict__ W, const float* __restrict__ Bv,
    float* __restrict__ Out) {
    __shared__ float as_[PK][PM + 4];
    __shared__ float bs[PK][PN + 4];
    __shared__ int inds[PM];

    const int tid = threadIdx.x;
    const int row0 = blockIdx.y * PM;
    const int col0 = blockIdx.x * PN;

    if (tid < PM) inds[tid] = ind[row0 + tid];
    __syncthreads();

    const int tx = tid & 15;
    const int ty = tid >> 4;

    float acc[4][4];
#pragma unroll
    for (int i = 0; i < 4; ++i)
#pragma unroll
        for (int j = 0; j < 4; ++j) acc[i][j] = 0.f;

    const int lm = tid >> 2;
    const int lk = (tid & 3) * 4;

    for (int kt = 0; kt < DIMK / PK; ++kt) {
        const int k0 = kt * PK;
        {
            float4 xv = *(const float4*)(X + (size_t)(row0 + lm) * DIMK + k0 + lk);
            float4 qv = *(const float4*)(E + (size_t)inds[lm] * DIMK + k0 + lk);
            as_[lk + 0][lm] = xv.x - qv.x;
            as_[lk + 1][lm] = xv.y - qv.y;
            as_[lk + 2][lm] = xv.z - qv.z;
            as_[lk + 3][lm] = xv.w - qv.w;
        }
        {
            float4 wv = *(const float4*)(W + (size_t)(col0 + lm) * DIMK + k0 + lk);
            bs[lk + 0][lm] = wv.x; bs[lk + 1][lm] = wv.y;
            bs[lk + 2][lm] = wv.z; bs[lk + 3][lm] = wv.w;
        }
        __syncthreads();
#pragma unroll
        for (int k = 0; k < PK; ++k) {
            float4 a = *(const float4*)&as_[k][ty * 4];
            float4 b = *(const float4*)&bs[k][tx * 4];
            float av[4] = {a.x, a.y, a.z, a.w};
            float bvv[4] = {b.x, b.y, b.z, b.w};
#pragma unroll
            for (int i = 0; i < 4; ++i)
#pragma unroll
                for (int j = 0; j < 4; ++j)
                    acc[i][j] = fmaf(av[i], bvv[j], acc[i][j]);
        }
        __syncthreads();
    }

#pragma unroll
    for (int j = 0; j < 4; ++j) {
        const int col = col0 + tx * 4 + j;
        const float bias = Bv[col];
#pragma unroll
        for (int i = 0; i < 4; ++i) {
            const int row = row0 + ty * 4 + i;
            Out[(size_t)row * DIMK + col] =
                X[(size_t)row * DIMK + col] + acc[i][j] + bias;
        }
    }
}

extern "C" void kernel_launch(void* const* d_in, const int* in_sizes, int n_in,
                              void* d_out, int out_size, void* d_ws, size_t ws_size,
                              hipStream_t stream) {
    const float* X = (const float*)d_in[0];
    const float* E = (const float*)d_in[1];
    const float* W = (const float*)d_in[2];
    const float* B = (const float*)d_in[3];
    float* out = (float*)d_out;

    const size_t packBytes = (size_t)NR * DIMK * 2;        // 8 MB each
    const size_t wPackBytes = (size_t)DIMK * DIMK * 2;     // 0.5 MB
    const size_t candBytes = (size_t)NR * NCAND * 8;       // 8 MB
    const size_t needMFMA =
        packBytes * 3 + wPackBytes + NE * 4 + candBytes + NR * 4 + 64;

    if (ws_size >= needMFMA) {
        uint8_t* Ap = (uint8_t*)d_ws;
        uint8_t* Bp = Ap + packBytes;
        uint8_t* Rp = Bp + packBytes;
        uint8_t* Wp = Rp + packBytes;
        float* enorm = (float*)(Wp + wPackBytes);
        uint2* candk = (uint2*)(enorm + NE);
        int* ind = (int*)((uint8_t*)candk + candBytes);

        hipLaunchKernelGGL(prep_kernel, dim3(NE / 4 + NR / 4 + DIMK / 4), dim3(256),
                           0, stream, X, E, W, Ap, Bp, Wp, enorm);
        hipLaunchKernelGGL(dist_mfma_kernel, dim3(1024), dim3(512), 0,
                           stream, Ap, Bp, enorm, candk);
        hipLaunchKernelGGL(refine_rpack_kernel, dim3(NR / 4), dim3(256), 0, stream,
                           X, E, candk, ind, Rp);
        hipLaunchKernelGGL(proj_mfma_kernel, dim3(256), dim3(256), 0, stream,
                           Rp, Wp, X, B, out);
    } else {
        float* enorm = (float*)d_ws;
        float* pval = enorm + NE;
        int* pidx = (int*)(pval + (size_t)NR * ESPLIT);
        int* ind = pidx + (size_t)NR * ESPLIT;

        hipLaunchKernelGGL(enorm_kernel, dim3(NE / 4), dim3(256), 0, stream, E, enorm);
        hipLaunchKernelGGL(dist_argmin_kernel, dim3(ESPLIT, NR / BM), dim3(256), 0,
                           stream, X, E, enorm, pval, pidx);
        hipLaunchKernelGGL(reduce_argmin_kernel, dim3(NR / 256), dim3(256), 0, stream,
                           pval, pidx, ind);
        hipLaunchKernelGGL(proj_kernel, dim3(DIMK / PN, NR / PM), dim3(256), 0, stream,
                           X, E, ind, W, B, out);
    }
}

// Round 13
// 114.580 us; speedup vs baseline: 1.1387x; 1.0087x over previous
//
#include <hip/hip_runtime.h>
#include <cstdint>

#define NR 8192
#define DIMK 512
#define NE 8192

// ---------------- MFMA path parameters ----------------
#define GBK 32              // K-step
#define KSTEPS (DIMK / GBK) // 16
#define TILE_BYTES 8192     // 128 rows x 32 k x 2B per K-step image
#define NBLK 64             // 64 col-blocks of 128 codes
#define NCAND 128           // candidate pairs per row (64 nb x 2 wc)
#define DELTA 6.0f          // refine window: bf16 err (~0.5) + key trunc (~2), margin

typedef __bf16 bf16x8 __attribute__((ext_vector_type(8)));
typedef float f32x4 __attribute__((ext_vector_type(4)));

// f32 fallback tiling
#define BM 128
#define BN 128
#define BK 16
#define ESPLIT 16
#define ERANGE (NE / ESPLIT)
#define ETILES (ERANGE / BN)
#define PM 64
#define PN 64
#define PK 16

// ---------------- Kernel: fused prep (enorm + E/X/W bf16 tiled pack) -----
// One wave handles one source row (64 lanes x 8 elems = 512).
// Block ranges: [0, NE/4)       -> E rows: norm + pack into Bp
//               [NE/4, +NR/4)   -> X rows: pack into Ap
//               [.., +DIMK/4)   -> W rows: pack into Wp
__global__ __launch_bounds__(256) void prep_kernel(
    const float* __restrict__ X, const float* __restrict__ E,
    const float* __restrict__ W,
    uint8_t* __restrict__ Ap, uint8_t* __restrict__ Bp,
    uint8_t* __restrict__ Wp, float* __restrict__ enorm) {
    const int bid = blockIdx.x;
    const int wave = threadIdx.x >> 6;
    const int lane = threadIdx.x & 63;

    const float* src;
    uint8_t* dst;
    int row;
    bool doNorm = false;
    if (bid < NE / 4) {
        row = bid * 4 + wave;
        src = E + (size_t)row * DIMK;
        dst = Bp;
        doNorm = true;
    } else if (bid < NE / 4 + NR / 4) {
        row = (bid - NE / 4) * 4 + wave;
        src = X + (size_t)row * DIMK;
        dst = Ap;
    } else {
        row = (bid - NE / 4 - NR / 4) * 4 + wave;
        src = W + (size_t)row * DIMK;
        dst = Wp;
    }

    float4 f0 = *(const float4*)(src + lane * 8);
    float4 f1 = *(const float4*)(src + lane * 8 + 4);
    float v[8] = {f0.x, f0.y, f0.z, f0.w, f1.x, f1.y, f1.z, f1.w};

    if (doNorm) {
        float s = 0.f;
#pragma unroll
        for (int j = 0; j < 8; ++j) s = fmaf(v[j], v[j], s);
#pragma unroll
        for (int off = 32; off > 0; off >>= 1) s += __shfl_xor(s, off, 64);
        if (lane == 0) enorm[row] = s;
    }

    unsigned short o[8];
#pragma unroll
    for (int j = 0; j < 8; ++j) {
        __bf16 h = (__bf16)v[j];
        o[j] = __builtin_bit_cast(unsigned short, h);
    }
    uint4 u;
    u.x = (uint32_t)o[0] | ((uint32_t)o[1] << 16);
    u.y = (uint32_t)o[2] | ((uint32_t)o[3] << 16);
    u.z = (uint32_t)o[4] | ((uint32_t)o[5] << 16);
    u.w = (uint32_t)o[6] | ((uint32_t)o[7] << 16);
    const int r = row & 127;
    const int kt = lane >> 2;
    const int kk = (lane & 3) * 8;
    size_t base = ((size_t)(row >> 7) * KSTEPS + kt) * TILE_BYTES;
    int byte = (r * 64 + kk * 2) ^ ((r & 7) << 4);
    *(uint4*)(dst + base + byte) = u;
}

// ---------------- Kernel: ||E_e||^2 (f32 fallback path only) -------------
__global__ __launch_bounds__(256) void enorm_kernel(const float* __restrict__ E,
                                                    float* __restrict__ enorm) {
    int wave = threadIdx.x >> 6;
    int lane = threadIdx.x & 63;
    int row = blockIdx.x * 4 + wave;
    const float* er = E + (size_t)row * DIMK;
    float s = 0.f;
#pragma unroll
    for (int k = 0; k < DIMK / 64; ++k) {
        float v = er[lane + k * 64];
        s = fmaf(v, v, s);
    }
#pragma unroll
    for (int off = 32; off > 0; off >>= 1) s += __shfl_down(s, off, 64);
    if (lane == 0) enorm[row] = s;
}

// ---------------- global -> LDS staging (8 KB, 256 threads) ----------------
__device__ __forceinline__ void stage_8k(void* lds, const void* g, int tid) {
    const int wid = tid >> 6;
    const int lane = tid & 63;
    using gu32 = const __attribute__((address_space(1))) uint32_t;
    using lu32 = __attribute__((address_space(3))) uint32_t;
    const uint8_t* gp = (const uint8_t*)g + (size_t)(wid * 1024 + lane * 16);
    uint8_t* lp = (uint8_t*)lds + wid * 1024;
    __builtin_amdgcn_global_load_lds((gu32*)gp, (lu32*)lp, 16, 0, 0);
    __builtin_amdgcn_global_load_lds((gu32*)(gp + 4096), (lu32*)(lp + 4096), 16, 0, 0);
}

// ---------------- 32-bit (value,index) key helpers ----------------
__device__ __forceinline__ unsigned flip32(float v) {
    unsigned b = __float_as_uint(v);
    return b ^ (0x80000000u | (unsigned)((int)b >> 31));
}
__device__ __forceinline__ float unflip32(unsigned b) {
    return __uint_as_float(b ^ (0x80000000u | ~(unsigned)((int)b >> 31)));
}

// ---------------- Kernel: bf16 MFMA dist + lane-local top-2 capture ------
// grid = 4096, one 128x128 tile per block; 2-barrier dbuf K-loop (this
// structure's measured ceiling: ~910 TF, MfmaUtil ~39% — r10/r11/r12
// established that tile growth and deep pipelines LOSE at K=512).
__global__ __launch_bounds__(256, 4) void dist_mfma_kernel(
    const uint8_t* __restrict__ Ap, const uint8_t* __restrict__ Bp,
    const float* __restrict__ enorm,
    uint2* __restrict__ candk) {
    __shared__ __align__(16) uint8_t As[2][TILE_BYTES];
    __shared__ __align__(16) uint8_t Bs[2][TILE_BYTES];

    const int tid = threadIdx.x;
    const int lane = tid & 63;
    const int wid = tid >> 6;
    const int wr = wid >> 1, wc = wid & 1;
    const int xcd = blockIdx.x & 7;
    const int slot = blockIdx.x >> 3;      // 0..511
    const int mb = slot >> 3;              // 0..63
    const int nb = xcd * 8 + (slot & 7);   // 0..63 (1MB L2-resident B/XCD)
    const int lr = lane & 15;
    const int kq = lane >> 4;

    const uint8_t* gA = Ap + (size_t)mb * KSTEPS * TILE_BYTES;
    const uint8_t* gB = Bp + (size_t)nb * KSTEPS * TILE_BYTES;

    int aoff[4], boff[4];
#pragma unroll
    for (int mi = 0; mi < 4; ++mi) {
        int row = wr * 64 + mi * 16 + lr;
        aoff[mi] = (row * 64 + kq * 16) ^ ((row & 7) << 4);
    }
#pragma unroll
    for (int ni = 0; ni < 4; ++ni) {
        int row = wc * 64 + ni * 16 + lr;
        boff[ni] = (row * 64 + kq * 16) ^ ((row & 7) << 4);
    }

    f32x4 acc[4][4];
#pragma unroll
    for (int mi = 0; mi < 4; ++mi)
#pragma unroll
        for (int ni = 0; ni < 4; ++ni)
            acc[mi][ni] = (f32x4){0.f, 0.f, 0.f, 0.f};

    stage_8k(As[0], gA, tid);
    stage_8k(Bs[0], gB, tid);

    int buf = 0;
    for (int kt = 0; kt < KSTEPS; ++kt) {
        __syncthreads();
        if (kt + 1 < KSTEPS) {
            stage_8k(As[buf ^ 1], gA + (size_t)(kt + 1) * TILE_BYTES, tid);
            stage_8k(Bs[buf ^ 1], gB + (size_t)(kt + 1) * TILE_BYTES, tid);
        }
        bf16x8 af[4], bfr[4];
#pragma unroll
        for (int mi = 0; mi < 4; ++mi) af[mi] = *(const bf16x8*)(As[buf] + aoff[mi]);
#pragma unroll
        for (int ni = 0; ni < 4; ++ni) bfr[ni] = *(const bf16x8*)(Bs[buf] + boff[ni]);
        // SWAPPED operands: lane holds xrow = lane&15; codes (lane>>4)*4+reg
#pragma unroll
        for (int mi = 0; mi < 4; ++mi)
#pragma unroll
            for (int ni = 0; ni < 4; ++ni)
                acc[mi][ni] = __builtin_amdgcn_mfma_f32_16x16x32_bf16(
                    bfr[ni], af[mi], acc[mi][ni], 0, 0, 0);
        buf ^= 1;
    }

    const int e0 = nb * 128 + wc * 64;
    float en[4][4];
#pragma unroll
    for (int ni = 0; ni < 4; ++ni)
#pragma unroll
        for (int reg = 0; reg < 4; ++reg)
            en[ni][reg] = enorm[e0 + ni * 16 + kq * 4 + reg];

#pragma unroll
    for (int mi = 0; mi < 4; ++mi) {
        unsigned k1 = 0xFFFFFFFFu, k2 = 0xFFFFFFFFu;
#pragma unroll
        for (int ni = 0; ni < 4; ++ni)
#pragma unroll
            for (int reg = 0; reg < 4; ++reg) {
                float s = fmaf(-2.f, acc[mi][ni][reg], en[ni][reg]);
                unsigned key = (flip32(s) & 0xFFFFE000u) |
                               (unsigned)(e0 + ni * 16 + kq * 4 + reg);
                unsigned lo = min(k1, key), hi = max(k1, key);
                k1 = lo;
                k2 = min(k2, hi);
            }
#pragma unroll
        for (int m = 16; m <= 32; m <<= 1) {
            unsigned o1 = __shfl_xor(k1, m, 64);
            unsigned o2 = __shfl_xor(k2, m, 64);
            unsigned lo = min(k1, o1), hi = max(k1, o1);
            k1 = lo;
            k2 = min(hi, min(k2, o2));
        }
        if (lane < 16) {
            int row = mb * 128 + wr * 64 + mi * 16 + lane;
            candk[(size_t)row * NCAND + nb * 2 + wc] = make_uint2(k1, k2);
        }
    }
}

// ------- Kernel: fp64 refine -> argmin, fused residual pack (bf16) -------
__global__ __launch_bounds__(256) void refine_rpack_kernel(
    const float* __restrict__ X, const float* __restrict__ E,
    const uint2* __restrict__ candk, int* __restrict__ ind,
    uint8_t* __restrict__ Rp) {
    const int wid = threadIdx.x >> 6;
    const int lane = threadIdx.x & 63;
    const int row = blockIdx.x * 4 + wid;

    const uint2* ck = candk + (size_t)row * NCAND;
    uint2 c0 = ck[lane];
    uint2 c1 = ck[lane + 64];
    unsigned keys[4] = {c0.x, c0.y, c1.x, c1.y};

    unsigned kmin = min(min(keys[0], keys[1]), min(keys[2], keys[3]));
#pragma unroll
    for (int off = 32; off > 0; off >>= 1)
        kmin = min(kmin, __shfl_xor(kmin, off, 64));

    const float vmin = unflip32(kmin & 0xFFFFE000u);
    const unsigned kthr = (flip32(vmin + DELTA) & 0xFFFFE000u) | 0x1FFFu;

    unsigned long long msk[4];
    int total = 0;
#pragma unroll
    for (int c = 0; c < 4; ++c) {
        msk[c] = __ballot(keys[c] <= kthr);
        total += __popcll(msk[c]);
    }

    const float* xr = X + (size_t)row * DIMK;
    int besti;
    if (total == 1) {
        besti = (int)(kmin & 0x1FFFu);
    } else {
        double bestd = 1e300;
        int bi = 0x7fffffff;
#pragma unroll 1
        for (int c = 0; c < 4; ++c) {
            unsigned long long mask = msk[c];
            while (mask) {
                int src = __ffsll((long long)mask) - 1;
                mask &= mask - 1;
                unsigned kk = __shfl(keys[c], src, 64);
                int e = (int)(kk & 0x1FFFu);
                const float* er = E + (size_t)e * DIMK;
                double s = 0.0;
#pragma unroll
                for (int j = 0; j < 8; ++j) {
                    double ev = (double)er[lane * 8 + j];
                    double xv = (double)xr[lane * 8 + j];
                    s += ev * (ev - 2.0 * xv);
                }
#pragma unroll
                for (int off = 32; off > 0; off >>= 1)
                    s += __shfl_xor(s, off, 64);
                if (s < bestd || (s == bestd && e < bi)) { bestd = s; bi = e; }
            }
        }
        besti = bi;
    }
    if (lane == 0) ind[row] = besti;

    // fused residual pack: R[row][k] = bf16(x - E[besti]), tiled+swizzled
    const float* er = E + (size_t)besti * DIMK;
    unsigned short o[8];
#pragma unroll
    for (int j = 0; j < 8; ++j) {
        __bf16 h = (__bf16)(xr[lane * 8 + j] - er[lane * 8 + j]);
        o[j] = __builtin_bit_cast(unsigned short, h);
    }
    uint4 u;
    u.x = (uint32_t)o[0] | ((uint32_t)o[1] << 16);
    u.y = (uint32_t)o[2] | ((uint32_t)o[3] << 16);
    u.z = (uint32_t)o[4] | ((uint32_t)o[5] << 16);
    u.w = (uint32_t)o[6] | ((uint32_t)o[7] << 16);
    int mbr = row >> 7, r = row & 127;
    int kt = lane >> 2, kk = (lane & 3) * 8;
    size_t base = ((size_t)mbr * KSTEPS + kt) * TILE_BYTES;
    int byte = (r * 64 + kk * 2) ^ ((r & 7) << 4);
    *(uint4*)(Rp + base + byte) = u;
}

// ------- Kernel: proj via bf16 MFMA: out = X + R @ W^T + b -------
__global__ __launch_bounds__(256, 4) void proj_mfma_kernel(
    const uint8_t* __restrict__ Rp, const uint8_t* __restrict__ Wp,
    const float* __restrict__ X, const float* __restrict__ Bv,
    float* __restrict__ Out) {
    __shared__ __align__(16) uint8_t As[2][TILE_BYTES];
    __shared__ __align__(16) uint8_t Bs[2][TILE_BYTES];

    const int tid = threadIdx.x;
    const int lane = tid & 63;
    const int wid = tid >> 6;
    const int wr = wid >> 1, wc = wid & 1;
    const int mb = blockIdx.x >> 2;   // 0..63 (x rows / 128)
    const int nb = blockIdx.x & 3;    // 0..3  (out cols / 128)
    const int lr = lane & 15;
    const int kq = lane >> 4;

    const uint8_t* gA = Rp + (size_t)mb * KSTEPS * TILE_BYTES;
    const uint8_t* gB = Wp + (size_t)nb * KSTEPS * TILE_BYTES;

    int aoff[4], boff[4];
#pragma unroll
    for (int mi = 0; mi < 4; ++mi) {
        int row = wr * 64 + mi * 16 + lr;
        aoff[mi] = (row * 64 + kq * 16) ^ ((row & 7) << 4);
    }
#pragma unroll
    for (int ni = 0; ni < 4; ++ni) {
        int row = wc * 64 + ni * 16 + lr;
        boff[ni] = (row * 64 + kq * 16) ^ ((row & 7) << 4);
    }

    f32x4 acc[4][4];
#pragma unroll
    for (int mi = 0; mi < 4; ++mi)
#pragma unroll
        for (int ni = 0; ni < 4; ++ni)
            acc[mi][ni] = (f32x4){0.f, 0.f, 0.f, 0.f};

    stage_8k(As[0], gA, tid);
    stage_8k(Bs[0], gB, tid);

    int buf = 0;
    for (int kt = 0; kt < KSTEPS; ++kt) {
        __syncthreads();
        if (kt + 1 < KSTEPS) {
            stage_8k(As[buf ^ 1], gA + (size_t)(kt + 1) * TILE_BYTES, tid);
            stage_8k(Bs[buf ^ 1], gB + (size_t)(kt + 1) * TILE_BYTES, tid);
        }
        bf16x8 af[4], bfr[4];
#pragma unroll
        for (int mi = 0; mi < 4; ++mi) af[mi] = *(const bf16x8*)(As[buf] + aoff[mi]);
#pragma unroll
        for (int ni = 0; ni < 4; ++ni) bfr[ni] = *(const bf16x8*)(Bs[buf] + boff[ni]);
#pragma unroll
        for (int mi = 0; mi < 4; ++mi)
#pragma unroll
            for (int ni = 0; ni < 4; ++ni)
                acc[mi][ni] = __builtin_amdgcn_mfma_f32_16x16x32_bf16(
                    af[mi], bfr[ni], acc[mi][ni], 0, 0, 0);
        buf ^= 1;
    }

    // epilogue: out[row][col] = X[row][col] + acc + bias[col]
    const int col0 = nb * 128 + wc * 64;
    float bias[4];
#pragma unroll
    for (int ni = 0; ni < 4; ++ni) bias[ni] = Bv[col0 + ni * 16 + lr];

#pragma unroll
    for (int mi = 0; mi < 4; ++mi) {
#pragma unroll
        for (int reg = 0; reg < 4; ++reg) {
            int row = mb * 128 + wr * 64 + mi * 16 + kq * 4 + reg;
            const float* xrow = X + (size_t)row * DIMK;
            float* orow = Out + (size_t)row * DIMK;
#pragma unroll
            for (int ni = 0; ni < 4; ++ni) {
                int col = col0 + ni * 16 + lr;
                orow[col] = xrow[col] + acc[mi][ni][reg] + bias[ni];
            }
        }
    }
}

// ------- f32 fallback: fused dist matmul + per-split argmin -------
__global__ __launch_bounds__(256) void dist_argmin_kernel(
    const float* __restrict__ X, const float* __restrict__ E,
    const float* __restrict__ enorm,
    float* __restrict__ pval, int* __restrict__ pidx) {
    __shared__ float xs[BK][BM + 4];
    __shared__ float es[BK][BN + 4];
    __shared__ float rv[BM][17];
    __shared__ int ri[BM][17];

    const int tid = threadIdx.x;
    const int row0 = blockIdx.y * BM;
    const int e_base = blockIdx.x * ERANGE;
    const int tx = tid & 15;
    const int ty = tid >> 4;

    float minv[8];
    int mini[8];
#pragma unroll
    for (int i = 0; i < 8; ++i) { minv[i] = 3.4e38f; mini[i] = 0; }

    const int lm = tid >> 1;
    const int lk = (tid & 1) * 8;

    for (int et = 0; et < ETILES; ++et) {
        const int e0 = e_base + et * BN;
        float acc[8][8];
#pragma unroll
        for (int i = 0; i < 8; ++i)
#pragma unroll
            for (int j = 0; j < 8; ++j) acc[i][j] = 0.f;

        for (int kt = 0; kt < DIMK / BK; ++kt) {
            const int k0 = kt * BK;
            {
                const float* src = X + (size_t)(row0 + lm) * DIMK + k0 + lk;
                float4 v0 = *(const float4*)(src);
                float4 v1 = *(const float4*)(src + 4);
                xs[lk + 0][lm] = v0.x; xs[lk + 1][lm] = v0.y;
                xs[lk + 2][lm] = v0.z; xs[lk + 3][lm] = v0.w;
                xs[lk + 4][lm] = v1.x; xs[lk + 5][lm] = v1.y;
                xs[lk + 6][lm] = v1.z; xs[lk + 7][lm] = v1.w;
            }
            {
                const float* src = E + (size_t)(e0 + lm) * DIMK + k0 + lk;
                float4 v0 = *(const float4*)(src);
                float4 v1 = *(const float4*)(src + 4);
                es[lk + 0][lm] = v0.x; es[lk + 1][lm] = v0.y;
                es[lk + 2][lm] = v0.z; es[lk + 3][lm] = v0.w;
                es[lk + 4][lm] = v1.x; es[lk + 5][lm] = v1.y;
                es[lk + 6][lm] = v1.z; es[lk + 7][lm] = v1.w;
            }
            __syncthreads();
#pragma unroll
            for (int k = 0; k < BK; ++k) {
                float4 a0 = *(const float4*)&xs[k][ty * 8];
                float4 a1 = *(const float4*)&xs[k][ty * 8 + 4];
                float4 b0 = *(const float4*)&es[k][tx * 8];
                float4 b1 = *(const float4*)&es[k][tx * 8 + 4];
                float av[8] = {a0.x, a0.y, a0.z, a0.w, a1.x, a1.y, a1.z, a1.w};
                float bv[8] = {b0.x, b0.y, b0.z, b0.w, b1.x, b1.y, b1.z, b1.w};
#pragma unroll
                for (int i = 0; i < 8; ++i)
#pragma unroll
                    for (int j = 0; j < 8; ++j)
                        acc[i][j] = fmaf(av[i], bv[j], acc[i][j]);
            }
            __syncthreads();
        }
#pragma unroll
        for (int j = 0; j < 8; ++j) {
            const int e = e0 + tx * 8 + j;
            const float en = enorm[e];
#pragma unroll
            for (int i = 0; i < 8; ++i) {
                const float s = fmaf(-2.f, acc[i][j], en);
                if (s < minv[i]) { minv[i] = s; mini[i] = e; }
            }
        }
    }
#pragma unroll
    for (int i = 0; i < 8; ++i) {
        rv[ty * 8 + i][tx] = minv[i];
        ri[ty * 8 + i][tx] = mini[i];
    }
    __syncthreads();
    if (tid < BM) {
        float bv = rv[tid][0];
        int bi = ri[tid][0];
#pragma unroll
        for (int t = 1; t < 16; ++t) {
            float vv = rv[tid][t];
            int ix = ri[tid][t];
            if (vv < bv || (vv == bv && ix < bi)) { bv = vv; bi = ix; }
        }
        const int row = row0 + tid;
        pval[(size_t)row * ESPLIT + blockIdx.x] = bv;
        pidx[(size_t)row * ESPLIT + blockIdx.x] = bi;
    }
}

__global__ __launch_bounds__(256) void reduce_argmin_kernel(
    const float* __restrict__ pval, const int* __restrict__ pidx,
    int* __restrict__ ind) {
    int r = blockIdx.x * blockDim.x + threadIdx.x;
    if (r >= NR) return;
    float bv = pval[(size_t)r * ESPLIT];
    int bi = pidx[(size_t)r * ESPLIT];
#pragma unroll
    for (int s = 1; s < ESPLIT; ++s) {
        float v = pval[(size_t)r * ESPLIT + s];
        int ix = pidx[(size_t)r * ESPLIT + s];
        if (v < bv || (v == bv && ix < bi)) { bv = v; bi = ix; }
    }
    ind[r] = bi;
}

// ------- f32 fallback proj: out = x + (x - E[ind]) @ W^T + b -------
__global__ __launch_bounds__(256) void proj_kernel(
    const float* __restrict__ X, const float* __restrict__ E,
    const int* __restrict__ ind,
    const float* __restrict__ W, const float* __restrict__ Bv,
    float* __restrict__ Out) {
    __shared__ float as_[PK][PM + 4];
    __shared__ float bs[PK][PN + 4];
    __shared__ int inds[PM];

    const int tid = threadIdx.x;
    const int row0 = blockIdx.y * PM;
    const int col0 = blockIdx.x * PN;

    if (tid < PM) inds[tid] = ind[row0 + tid];
    __syncthreads();

    const int tx = tid & 15;
    const int ty = tid >> 4;

    float acc[4][4];
#pragma unroll
    for (int i = 0; i < 4; ++i)
#pragma unroll
        for (int j = 0; j < 4; ++j) acc[i][j] = 0.f;

    const int lm = tid >> 2;
    const int lk = (tid & 3) * 4;

    for (int kt = 0; kt < DIMK / PK; ++kt) {
        const int k0 = kt * PK;
        {
            float4 xv = *(const float4*)(X + (size_t)(row0 + lm) * DIMK + k0 + lk);
            float4 qv = *(const float4*)(E + (size_t)inds[lm] * DIMK + k0 + lk);
            as_[lk + 0][lm] = xv.x - qv.x;
            as_[lk + 1][lm] = xv.y - qv.y;
            as_[lk + 2][lm] = xv.z - qv.z;
            as_[lk + 3][lm] = xv.w - qv.w;
        }
        {
            float4 wv = *(const float4*)(W + (size_t)(col0 + lm) * DIMK + k0 + lk);
            bs[lk + 0][lm] = wv.x; bs[lk + 1][lm] = wv.y;
            bs[lk + 2][lm] = wv.z; bs[lk + 3][lm] = wv.w;
        }
        __syncthreads();
#pragma unroll
        for (int k = 0; k < PK; ++k) {
            float4 a = *(const float4*)&as_[k][ty * 4];
            float4 b = *(const float4*)&bs[k][tx * 4];
            float av[4] = {a.x, a.y, a.z, a.w};
            float bvv[4] = {b.x, b.y, b.z, b.w};
#pragma unroll
            for (int i = 0; i < 4; ++i)
#pragma unroll
                for (int j = 0; j < 4; ++j)
                    acc[i][j] = fmaf(av[i], bvv[j], acc[i][j]);
        }
        __syncthreads();
    }

#pragma unroll
    for (int j = 0; j < 4; ++j) {
        const int col = col0 + tx * 4 + j;
        const float bias = Bv[col];
#pragma unroll
        for (int i = 0; i < 4; ++i) {
            const int row = row0 + ty * 4 + i;
            Out[(size_t)row * DIMK + col] =
                X[(size_t)row * DIMK + col] + acc[i][j] + bias;
        }
    }
}

extern "C" void kernel_launch(void* const* d_in, const int* in_sizes, int n_in,
                              void* d_out, int out_size, void* d_ws, size_t ws_size,
                              hipStream_t stream) {
    const float* X = (const float*)d_in[0];
    const float* E = (const float*)d_in[1];
    const float* W = (const float*)d_in[2];
    const float* B = (const float*)d_in[3];
    float* out = (float*)d_out;

    const size_t packBytes = (size_t)NR * DIMK * 2;        // 8 MB each
    const size_t wPackBytes = (size_t)DIMK * DIMK * 2;     // 0.5 MB
    const size_t candBytes = (size_t)NR * NCAND * 8;       // 8 MB
    const size_t needMFMA =
        packBytes * 3 + wPackBytes + NE * 4 + candBytes + NR * 4 + 64;

    if (ws_size >= needMFMA) {
        uint8_t* Ap = (uint8_t*)d_ws;
        uint8_t* Bp = Ap + packBytes;
        uint8_t* Rp = Bp + packBytes;
        uint8_t* Wp = Rp + packBytes;
        float* enorm = (float*)(Wp + wPackBytes);
        uint2* candk = (uint2*)(enorm + NE);
        int* ind = (int*)((uint8_t*)candk + candBytes);

        hipLaunchKernelGGL(prep_kernel, dim3(NE / 4 + NR / 4 + DIMK / 4), dim3(256),
                           0, stream, X, E, W, Ap, Bp, Wp, enorm);
        hipLaunchKernelGGL(dist_mfma_kernel, dim3(4096), dim3(256), 0,
                           stream, Ap, Bp, enorm, candk);
        hipLaunchKernelGGL(refine_rpack_kernel, dim3(NR / 4), dim3(256), 0, stream,
                           X, E, candk, ind, Rp);
        hipLaunchKernelGGL(proj_mfma_kernel, dim3(256), dim3(256), 0, stream,
                           Rp, Wp, X, B, out);
    } else {
        float* enorm = (float*)d_ws;
        float* pval = enorm + NE;
        int* pidx = (int*)(pval + (size_t)NR * ESPLIT);
        int* ind = pidx + (size_t)NR * ESPLIT;

        hipLaunchKernelGGL(enorm_kernel, dim3(NE / 4), dim3(256), 0, stream, E, enorm);
        hipLaunchKernelGGL(dist_argmin_kernel, dim3(ESPLIT, NR / BM), dim3(256), 0,
                           stream, X, E, enorm, pval, pidx);
        hipLaunchKernelGGL(reduce_argmin_kernel, dim3(NR / 256), dim3(256), 0, stream,
                           pval, pidx, ind);
        hipLaunchKernelGGL(proj_kernel, dim3(DIMK / PN, NR / PM), dim3(256), 0, stream,
                           X, E, ind, W, B, out);
    }
}